// Round 5
// baseline (2780.483 us; speedup 1.0000x reference)
//
#include <hip/hip_runtime.h>
#include <cstdint>
#include <cstddef>

#define EE 1000000
#define NN 100000
#define NT 62500   // EE / 16 edges per wave-tile (exact, no tail)

typedef unsigned short u16;
typedef __bf16 bf16x8 __attribute__((ext_vector_type(8)));
typedef float f32x4 __attribute__((ext_vector_type(4)));

__device__ __forceinline__ u16 f2bf(float f) {
    union { float f; uint32_t u; } v; v.f = f;
    uint32_t r = v.u + 0x7FFFu + ((v.u >> 16) & 1u);   // RNE
    return (u16)(r >> 16);
}
// RNE bf16 pair pack (compiler emits v_cvt_pk_bf16_f32)
__device__ __forceinline__ uint32_t cvt2(float lo, float hi) {
    u16 a = __builtin_bit_cast(u16, (__bf16)lo);
    u16 b = __builtin_bit_cast(u16, (__bf16)hi);
    return (uint32_t)a | ((uint32_t)b << 16);
}

// ---------------- prep: pack weights into MFMA A-operand fragment streams.
// W1^T  A-frags (16x16x32): pack[((rt*12+kt)*64+lane)*8+j]
//        = W1[kt*32 + (lane>>4)*8 + j][rt*16 + (lane&15)]
// W2^T  A-frags with K-permutation d(q)=64*(j>>2)+16*kt2+4*g+(j&3) so GEMM1's
//        accumulator feeds GEMM2's B-fragment with zero cross-lane traffic:
//        pack[49152 + ((ot*4+kt2)*64+lane)*8+j]
//        = W2[64*(j>>2)+16*kt2+4*((lane>>4)&3)+(j&3)][ot*16 + (lane&15)]
// consts at pack+65536 (as f32): b1[128], b2[128], ln_g[128], ln_b[128]
__global__ void pack_weights_k(const float* __restrict__ W1, const float* __restrict__ W2,
                               const float* __restrict__ b1, const float* __restrict__ b2,
                               const float* __restrict__ lng, const float* __restrict__ lnb,
                               u16* __restrict__ pack) {
    int t = blockIdx.x * 256 + threadIdx.x;
    if (t < 49152) {
        int j = t & 7, lane = (t >> 3) & 63;
        int rem = t >> 9;          // rt*12 + kt
        int kt = rem % 12, rt = rem / 12;
        int k = kt * 32 + ((lane >> 4) & 3) * 8 + j;
        int hid = rt * 16 + (lane & 15);
        pack[t] = f2bf(W1[k * 128 + hid]);
    } else if (t < 65536) {
        int u = t - 49152;
        int j = u & 7, lane = (u >> 3) & 63;
        int kt2 = (u >> 9) & 3, ot = u >> 11;
        int hidden = 64 * (j >> 2) + 16 * kt2 + 4 * ((lane >> 4) & 3) + (j & 3);
        int outd = ot * 16 + (lane & 15);
        pack[t] = f2bf(W2[hidden * 128 + outd]);
    } else if (t < 66048) {
        int i = t - 65536;
        float v = (i < 128) ? b1[i] : (i < 256) ? b2[i - 128]
                : (i < 384) ? lng[i - 256] : lnb[i - 384];
        ((float*)(pack + 65536))[i] = v;
    }
}

// ---------------- output[1] = nfeat passthrough
__global__ void copy_nfeat_k(const float4* __restrict__ s, float4* __restrict__ d, int n) {
    for (int i = blockIdx.x * blockDim.x + threadIdx.x; i < n; i += gridDim.x * blockDim.x)
        d[i] = s[i];
}

// ---------------- main fused kernel: barrier-free per-wave tiles.
// 1024 threads = 16 waves, 1 block/CU (130 KB LDS). __launch_bounds__(1024,4)
// pins the VGPR cap at 128 (R4's failure: default bounds targeted 64 -> spill).
// Each wave owns 16 edges/tile: cat^T B-frags gathered straight from global with
// a 2-deep rolling float window (16 VGPR), A-frags (W1^T/W2^T) broadcast from
// LDS. No __syncthreads in the loop; 16 waves/CU provide latency tolerance.
__global__ void __launch_bounds__(1024, 4)
edge_mlp_k(const float* __restrict__ efeat, const float* __restrict__ nfeat,
           const int* __restrict__ srci, const int* __restrict__ dsti,
           const u16* __restrict__ pack, float* __restrict__ out) {
    extern __shared__ char smem[];
    const u16* w1 = (const u16*)smem;            // 96 KB: W1^T frags
    const u16* w2 = (const u16*)(smem + 98304);  // 32 KB: W2^T frags
    const float* cst = (const float*)(smem + 131072); // 2 KB consts

    const int tid = threadIdx.x;
    // stage weights + consts (only sync in the kernel)
    {
        const uint4* gsrc = (const uint4*)pack;   // 131072 B = 8192 uint4
        uint4* l = (uint4*)smem;
#pragma unroll
        for (int i = 0; i < 8; i++) l[tid + i * 1024] = gsrc[tid + i * 1024];
        if (tid < 512) ((float*)(smem + 131072))[tid] = ((const float*)(pack + 65536))[tid];
    }
    __syncthreads();

    const int lane = tid & 63;
    const int wid = tid >> 6;
    const int col = lane & 15;          // edge slot within tile
    const int g4 = (lane >> 4) & 3;     // k-/row-group

    const float* cb1 = cst;
    const float* cb2 = cst + 128;
    const float* cg = cst + 256;
    const float* cbb = cst + 384;

    int wt = blockIdx.x * 16 + wid;
    const int stride = (int)gridDim.x * 16;

    // tile-0 pointers + prime the 2-deep window with kt0,kt1 (efeat quarters)
    int e0 = wt * 16 + col;
    const float* rowE = efeat + (size_t)e0 * 128;
    const float* rowS = nfeat + (size_t)srci[e0] * 128;
    const float* rowD = nfeat + (size_t)dsti[e0] * 128;

    float4 f0a, f0b, f1a, f1b;
    {
        const float4* p0 = (const float4*)(rowE + g4 * 8);
        f0a = p0[0]; f0b = p0[1];
        const float4* p1 = (const float4*)(rowE + 32 + g4 * 8);
        f1a = p1[0]; f1b = p1[1];
    }

    // STEP(KT, FA, FB, NPTR, NQ): convert slot -> bf16 frag, re-issue the freed
    // slot with quarter NQ of row NPTR (used at step KT+2), run 8 MFMAs.
#define STEP(KT, FA, FB, NPTR, NQ) { \
        bf16x8 bf_; uint32_t* bu_ = (uint32_t*)&bf_; \
        bu_[0] = cvt2(FA.x, FA.y); bu_[1] = cvt2(FA.z, FA.w); \
        bu_[2] = cvt2(FB.x, FB.y); bu_[3] = cvt2(FB.z, FB.w); \
        { const float4* p_ = (const float4*)((NPTR) + (NQ) * 32 + g4 * 8); \
          FA = p_[0]; FB = p_[1]; } \
        _Pragma("unroll") \
        for (int rt = 0; rt < 8; rt++) { \
            bf16x8 a_ = *(const bf16x8*)(w1 + ((rt * 12 + (KT)) * 64 + lane) * 8); \
            acc1[rt] = __builtin_amdgcn_mfma_f32_16x16x32_bf16(a_, bf_, acc1[rt], 0, 0, 0); \
        } }

    for (; wt < NT; wt += stride) {
        // next-tile bookkeeping; index gathers have GEMM1+GEMM2+LN to land
        const int wtn = wt + stride;
        const int en = ((wtn < NT) ? wtn : wt) * 16 + col;
        const int sn = srci[en];
        const int dn = dsti[en];
        const float* rowEn = efeat + (size_t)en * 128;

        // ---- GEMM1: h^T[128 x 16] = W1^T · cat^T
        // kt source map: 0-3 rowE, 4-7 rowS, 8-11 rowD; steps 10/11 preload the
        // NEXT tile's kt0/kt1 (rowEn — address needs no index) to chain tiles.
        f32x4 acc1[8] = {};
        STEP(0,  f0a, f0b, rowE, 2)
        STEP(1,  f1a, f1b, rowE, 3)
        STEP(2,  f0a, f0b, rowS, 0)
        STEP(3,  f1a, f1b, rowS, 1)
        STEP(4,  f0a, f0b, rowS, 2)
        STEP(5,  f1a, f1b, rowS, 3)
        STEP(6,  f0a, f0b, rowD, 0)
        STEP(7,  f1a, f1b, rowD, 1)
        STEP(8,  f0a, f0b, rowD, 2)
        STEP(9,  f1a, f1b, rowD, 3)
        STEP(10, f0a, f0b, rowEn, 0)
        STEP(11, f1a, f1b, rowEn, 1)

        // ---- bias1 + SiLU -> packed bf16 (acc1 dies here)
        uint32_t hpk[8][2];
#pragma unroll
        for (int rt = 0; rt < 8; rt++) {
            float4 b1v = *(const float4*)(cb1 + rt * 16 + g4 * 4);
            float x0 = acc1[rt][0] + b1v.x, x1 = acc1[rt][1] + b1v.y;
            float x2 = acc1[rt][2] + b1v.z, x3 = acc1[rt][3] + b1v.w;
            float s0 = x0 / (1.f + __expf(-x0)), s1 = x1 / (1.f + __expf(-x1));
            float s2 = x2 / (1.f + __expf(-x2)), s3 = x3 / (1.f + __expf(-x3));
            hpk[rt][0] = cvt2(s0, s1);
            hpk[rt][1] = cvt2(s2, s3);
        }

        // ---- residual loads early so they overlap GEMM2 (rowE is L1/L2-hot)
        float4 ef4[8];
#pragma unroll
        for (int ot = 0; ot < 8; ot++)
            ef4[ot] = *(const float4*)(rowE + ot * 16 + g4 * 4);

        // ---- GEMM2: out^T[128 x 16] = W2^T(perm) · h^T (B straight from hpk)
        f32x4 acc2[8] = {};
#pragma unroll
        for (int kt2 = 0; kt2 < 4; kt2++) {
            bf16x8 bf;
            {
                uint32_t* bu = (uint32_t*)&bf;
                bu[0] = hpk[kt2][0]; bu[1] = hpk[kt2][1];
                bu[2] = hpk[kt2 + 4][0]; bu[3] = hpk[kt2 + 4][1];
            }
#pragma unroll
            for (int ot = 0; ot < 8; ot++) {
                bf16x8 a = *(const bf16x8*)(w2 + ((ot * 4 + kt2) * 64 + lane) * 8);
                acc2[ot] = __builtin_amdgcn_mfma_f32_16x16x32_bf16(a, bf, acc2[ot], 0, 0, 0);
            }
        }

        // ---- + b2, LN stats (per edge: in-lane 32 + shfl over the 4 groups)
        float s = 0.f, q = 0.f;
#pragma unroll
        for (int ot = 0; ot < 8; ot++) {
            float4 b2v = *(const float4*)(cb2 + ot * 16 + g4 * 4);
#pragma unroll
            for (int r = 0; r < 4; r++) {
                float x = acc2[ot][r] + ((const float*)&b2v)[r];
                acc2[ot][r] = x;
                s += x; q += x * x;
            }
        }
        s += __shfl_xor(s, 16); q += __shfl_xor(q, 16);
        s += __shfl_xor(s, 32); q += __shfl_xor(q, 32);
        const float mean = s * (1.f / 128.f);
        const float rstd = rsqrtf(q * (1.f / 128.f) - mean * mean + 1e-5f);

        // ---- scale/shift + residual, store (out^T frag -> row-major out)
        float* op = out + (size_t)(wt * 16 + col) * 128;
#pragma unroll
        for (int ot = 0; ot < 8; ot++) {
            float4 gv = *(const float4*)(cg + ot * 16 + g4 * 4);
            float4 bv = *(const float4*)(cbb + ot * 16 + g4 * 4);
            float4 o;
            o.x = (acc2[ot][0] - mean) * rstd * gv.x + bv.x + ef4[ot].x;
            o.y = (acc2[ot][1] - mean) * rstd * gv.y + bv.y + ef4[ot].y;
            o.z = (acc2[ot][2] - mean) * rstd * gv.z + bv.z + ef4[ot].z;
            o.w = (acc2[ot][3] - mean) * rstd * gv.w + bv.w + ef4[ot].w;
            *(float4*)(op + ot * 16 + g4 * 4) = o;
        }

        rowE = rowEn;
        rowS = nfeat + (size_t)sn * 128;
        rowD = nfeat + (size_t)dn * 128;
    }
#undef STEP
}

extern "C" void kernel_launch(void* const* d_in, const int* in_sizes, int n_in,
                              void* d_out, int out_size, void* d_ws, size_t ws_size,
                              hipStream_t stream) {
    const float* efeat = (const float*)d_in[0];
    const float* nfeat = (const float*)d_in[1];
    const int* srci = (const int*)d_in[2];
    const int* dsti = (const int*)d_in[3];
    const float* W1 = (const float*)d_in[4];
    const float* b1 = (const float*)d_in[5];
    const float* W2 = (const float*)d_in[6];
    const float* b2 = (const float*)d_in[7];
    const float* lng = (const float*)d_in[8];
    const float* lnb = (const float*)d_in[9];
    float* out = (float*)d_out;

    // 130 KB pack buffer (128 KB bf16 weights + 2 KB consts); fall back to the
    // (later overwritten) nfeat output region if the workspace is too small.
    u16* pack = (ws_size >= 133120) ? (u16*)d_ws : (u16*)(out + (size_t)EE * 128);

    hipFuncSetAttribute(reinterpret_cast<const void*>(edge_mlp_k),
                        hipFuncAttributeMaxDynamicSharedMemorySize, 133120);

    pack_weights_k<<<258, 256, 0, stream>>>(W1, W2, b1, b2, lng, lnb, pack);
    edge_mlp_k<<<256, 1024, 133120, stream>>>(efeat, nfeat, srci, dsti, pack, out);
    copy_nfeat_k<<<2048, 256, 0, stream>>>((const float4*)nfeat,
                                           (float4*)(out + (size_t)EE * 128),
                                           (NN * 128) / 4);
}

// Round 6
// 2260.693 us; speedup vs baseline: 1.2299x; 1.2299x over previous
//
#include <hip/hip_runtime.h>
#include <cstdint>
#include <cstddef>

#define EE 1000000
#define NN 100000
#define NT 62500   // EE / 16 edges per wave-tile (exact, no tail)

typedef unsigned short u16;
typedef __bf16 bf16x8 __attribute__((ext_vector_type(8)));
typedef float f32x4 __attribute__((ext_vector_type(4)));

__device__ __forceinline__ u16 f2bf(float f) {
    union { float f; uint32_t u; } v; v.f = f;
    uint32_t r = v.u + 0x7FFFu + ((v.u >> 16) & 1u);   // RNE
    return (u16)(r >> 16);
}
// RNE bf16 pair pack (compiler emits v_cvt_pk_bf16_f32)
__device__ __forceinline__ uint32_t cvt2(float lo, float hi) {
    u16 a = __builtin_bit_cast(u16, (__bf16)lo);
    u16 b = __builtin_bit_cast(u16, (__bf16)hi);
    return (uint32_t)a | ((uint32_t)b << 16);
}

// ---------------- prep: pack weights into MFMA A-operand fragment streams.
// W1^T  A-frags (16x16x32): pack[((rt*12+kt)*64+lane)*8+j]
//        = W1[kt*32 + (lane>>4)*8 + j][rt*16 + (lane&15)]
// W2^T  A-frags with K-permutation d(q)=64*(j>>2)+16*kt2+4*g+(j&3) so GEMM1's
//        accumulator feeds GEMM2's B-fragment with zero cross-lane traffic:
//        pack[49152 + ((ot*4+kt2)*64+lane)*8+j]
//        = W2[64*(j>>2)+16*kt2+4*((lane>>4)&3)+(j&3)][ot*16 + (lane&15)]
// consts at pack+65536 (as f32): b1[128], b2[128], ln_g[128], ln_b[128]
__global__ void pack_weights_k(const float* __restrict__ W1, const float* __restrict__ W2,
                               const float* __restrict__ b1, const float* __restrict__ b2,
                               const float* __restrict__ lng, const float* __restrict__ lnb,
                               u16* __restrict__ pack) {
    int t = blockIdx.x * 256 + threadIdx.x;
    if (t < 49152) {
        int j = t & 7, lane = (t >> 3) & 63;
        int rem = t >> 9;          // rt*12 + kt
        int kt = rem % 12, rt = rem / 12;
        int k = kt * 32 + ((lane >> 4) & 3) * 8 + j;
        int hid = rt * 16 + (lane & 15);
        pack[t] = f2bf(W1[k * 128 + hid]);
    } else if (t < 65536) {
        int u = t - 49152;
        int j = u & 7, lane = (u >> 3) & 63;
        int kt2 = (u >> 9) & 3, ot = u >> 11;
        int hidden = 64 * (j >> 2) + 16 * kt2 + 4 * ((lane >> 4) & 3) + (j & 3);
        int outd = ot * 16 + (lane & 15);
        pack[t] = f2bf(W2[hidden * 128 + outd]);
    } else if (t < 66048) {
        int i = t - 65536;
        float v = (i < 128) ? b1[i] : (i < 256) ? b2[i - 128]
                : (i < 384) ? lng[i - 256] : lnb[i - 384];
        ((float*)(pack + 65536))[i] = v;
    }
}

// ---------------- output[1] = nfeat passthrough
__global__ void copy_nfeat_k(const float4* __restrict__ s, float4* __restrict__ d, int n) {
    for (int i = blockIdx.x * blockDim.x + threadIdx.x; i < n; i += gridDim.x * blockDim.x)
        d[i] = s[i];
}

// ---------------- main fused kernel: barrier-free per-wave tiles.
// 512 threads = 8 waves, 1 block/CU (130 KB LDS). Empirical hipcc rule (R4/R5):
// 1024-thread blocks get force-capped at 64 VGPR -> massive spill; 512-thread
// blocks allocate 120-128 VGPR spill-free (R1/R3). Each wave owns 16 edges per
// tile: cat^T B-frags gathered straight from global with a 3-deep rolling float
// window (24 VGPR), A-frags (W1^T/W2^T) broadcast-read from LDS. No
// __syncthreads in the loop.
__global__ void __launch_bounds__(512)
edge_mlp_k(const float* __restrict__ efeat, const float* __restrict__ nfeat,
           const int* __restrict__ srci, const int* __restrict__ dsti,
           const u16* __restrict__ pack, float* __restrict__ out) {
    extern __shared__ char smem[];
    const u16* w1 = (const u16*)smem;            // 96 KB: W1^T frags
    const u16* w2 = (const u16*)(smem + 98304);  // 32 KB: W2^T frags
    const float* cst = (const float*)(smem + 131072); // 2 KB consts

    const int tid = threadIdx.x;
    // stage weights + consts (only sync in the kernel)
    {
        const uint4* gsrc = (const uint4*)pack;   // 131072 B = 8192 uint4
        uint4* l = (uint4*)smem;
#pragma unroll
        for (int i = 0; i < 16; i++) l[tid + i * 512] = gsrc[tid + i * 512];
        ((float*)(smem + 131072))[tid] = ((const float*)(pack + 65536))[tid];
    }
    __syncthreads();

    const int lane = tid & 63;
    const int wid = tid >> 6;           // 0..7
    const int col = lane & 15;          // edge slot within tile
    const int g4 = (lane >> 4) & 3;     // k-/row-group

    const float* cb1 = cst;
    const float* cb2 = cst + 128;
    const float* cg = cst + 256;
    const float* cbb = cst + 384;

    int wt = blockIdx.x * 8 + wid;
    const int stride = (int)gridDim.x * 8;

    // tile-0 pointers + prime the 3-deep window with kt0..kt2 (efeat quarters)
    int e0 = wt * 16 + col;
    const float* rowE = efeat + (size_t)e0 * 128;
    const float* rowS = nfeat + (size_t)srci[e0] * 128;
    const float* rowD = nfeat + (size_t)dsti[e0] * 128;

    float4 f0a, f0b, f1a, f1b, f2a, f2b;
    {
        const float4* p0 = (const float4*)(rowE + g4 * 8);
        f0a = p0[0]; f0b = p0[1];
        const float4* p1 = (const float4*)(rowE + 32 + g4 * 8);
        f1a = p1[0]; f1b = p1[1];
        const float4* p2 = (const float4*)(rowE + 64 + g4 * 8);
        f2a = p2[0]; f2b = p2[1];
    }

    // STEP(KT, FA, FB, NPTR, NQ): convert slot -> bf16 frag, re-issue the freed
    // slot with quarter NQ of row NPTR (consumed at step KT+3), run 8 MFMAs.
#define STEP(KT, FA, FB, NPTR, NQ) { \
        bf16x8 bf_; uint32_t* bu_ = (uint32_t*)&bf_; \
        bu_[0] = cvt2(FA.x, FA.y); bu_[1] = cvt2(FA.z, FA.w); \
        bu_[2] = cvt2(FB.x, FB.y); bu_[3] = cvt2(FB.z, FB.w); \
        { const float4* p_ = (const float4*)((NPTR) + (NQ) * 32 + g4 * 8); \
          FA = p_[0]; FB = p_[1]; } \
        _Pragma("unroll") \
        for (int rt = 0; rt < 8; rt++) { \
            bf16x8 a_ = *(const bf16x8*)(w1 + ((rt * 12 + (KT)) * 64 + lane) * 8); \
            acc1[rt] = __builtin_amdgcn_mfma_f32_16x16x32_bf16(a_, bf_, acc1[rt], 0, 0, 0); \
        } }

    for (; wt < NT; wt += stride) {
        // next-tile bookkeeping; index gathers have GEMM1+GEMM2+LN to land
        const int wtn = wt + stride;
        const int en = ((wtn < NT) ? wtn : wt) * 16 + col;
        const int sn = srci[en];
        const int dn = dsti[en];
        const float* rowEn = efeat + (size_t)en * 128;

        // ---- GEMM1: h^T[128 x 16] = W1^T · cat^T
        // kt source map: 0-3 rowE, 4-7 rowS, 8-11 rowD; steps 9-11 preload the
        // NEXT tile's kt0-2 (rowEn — address needs no index) to chain tiles.
        f32x4 acc1[8] = {};
        STEP(0,  f0a, f0b, rowE, 3)
        STEP(1,  f1a, f1b, rowS, 0)
        STEP(2,  f2a, f2b, rowS, 1)
        STEP(3,  f0a, f0b, rowS, 2)
        STEP(4,  f1a, f1b, rowS, 3)
        STEP(5,  f2a, f2b, rowD, 0)
        STEP(6,  f0a, f0b, rowD, 1)
        STEP(7,  f1a, f1b, rowD, 2)
        STEP(8,  f2a, f2b, rowD, 3)
        STEP(9,  f0a, f0b, rowEn, 0)
        STEP(10, f1a, f1b, rowEn, 1)
        STEP(11, f2a, f2b, rowEn, 2)

        // ---- bias1 + SiLU -> packed bf16 (acc1 dies here)
        uint32_t hpk[8][2];
#pragma unroll
        for (int rt = 0; rt < 8; rt++) {
            float4 b1v = *(const float4*)(cb1 + rt * 16 + g4 * 4);
            float x0 = acc1[rt][0] + b1v.x, x1 = acc1[rt][1] + b1v.y;
            float x2 = acc1[rt][2] + b1v.z, x3 = acc1[rt][3] + b1v.w;
            float s0 = x0 / (1.f + __expf(-x0)), s1 = x1 / (1.f + __expf(-x1));
            float s2 = x2 / (1.f + __expf(-x2)), s3 = x3 / (1.f + __expf(-x3));
            hpk[rt][0] = cvt2(s0, s1);
            hpk[rt][1] = cvt2(s2, s3);
        }

        // ---- residual loads early so they overlap GEMM2 (rowE is L1/L2-hot)
        float4 ef4[8];
#pragma unroll
        for (int ot = 0; ot < 8; ot++)
            ef4[ot] = *(const float4*)(rowE + ot * 16 + g4 * 4);

        // ---- GEMM2: out^T[128 x 16] = W2^T(perm) · h^T (B straight from hpk)
        f32x4 acc2[8] = {};
#pragma unroll
        for (int kt2 = 0; kt2 < 4; kt2++) {
            bf16x8 bf;
            {
                uint32_t* bu = (uint32_t*)&bf;
                bu[0] = hpk[kt2][0]; bu[1] = hpk[kt2][1];
                bu[2] = hpk[kt2 + 4][0]; bu[3] = hpk[kt2 + 4][1];
            }
#pragma unroll
            for (int ot = 0; ot < 8; ot++) {
                bf16x8 a = *(const bf16x8*)(w2 + ((ot * 4 + kt2) * 64 + lane) * 8);
                acc2[ot] = __builtin_amdgcn_mfma_f32_16x16x32_bf16(a, bf, acc2[ot], 0, 0, 0);
            }
        }

        // ---- + b2, LN stats (per edge: in-lane 32 + shfl over the 4 groups)
        float s = 0.f, q = 0.f;
#pragma unroll
        for (int ot = 0; ot < 8; ot++) {
            float4 b2v = *(const float4*)(cb2 + ot * 16 + g4 * 4);
#pragma unroll
            for (int r = 0; r < 4; r++) {
                float x = acc2[ot][r] + ((const float*)&b2v)[r];
                acc2[ot][r] = x;
                s += x; q += x * x;
            }
        }
        s += __shfl_xor(s, 16); q += __shfl_xor(q, 16);
        s += __shfl_xor(s, 32); q += __shfl_xor(q, 32);
        const float mean = s * (1.f / 128.f);
        const float rstd = rsqrtf(q * (1.f / 128.f) - mean * mean + 1e-5f);

        // ---- scale/shift + residual, store (out^T frag -> row-major out)
        float* op = out + (size_t)(wt * 16 + col) * 128;
#pragma unroll
        for (int ot = 0; ot < 8; ot++) {
            float4 gv = *(const float4*)(cg + ot * 16 + g4 * 4);
            float4 bv = *(const float4*)(cbb + ot * 16 + g4 * 4);
            float4 o;
            o.x = (acc2[ot][0] - mean) * rstd * gv.x + bv.x + ef4[ot].x;
            o.y = (acc2[ot][1] - mean) * rstd * gv.y + bv.y + ef4[ot].y;
            o.z = (acc2[ot][2] - mean) * rstd * gv.z + bv.z + ef4[ot].z;
            o.w = (acc2[ot][3] - mean) * rstd * gv.w + bv.w + ef4[ot].w;
            *(float4*)(op + ot * 16 + g4 * 4) = o;
        }

        rowE = rowEn;
        rowS = nfeat + (size_t)sn * 128;
        rowD = nfeat + (size_t)dn * 128;
    }
#undef STEP
}

extern "C" void kernel_launch(void* const* d_in, const int* in_sizes, int n_in,
                              void* d_out, int out_size, void* d_ws, size_t ws_size,
                              hipStream_t stream) {
    const float* efeat = (const float*)d_in[0];
    const float* nfeat = (const float*)d_in[1];
    const int* srci = (const int*)d_in[2];
    const int* dsti = (const int*)d_in[3];
    const float* W1 = (const float*)d_in[4];
    const float* b1 = (const float*)d_in[5];
    const float* W2 = (const float*)d_in[6];
    const float* b2 = (const float*)d_in[7];
    const float* lng = (const float*)d_in[8];
    const float* lnb = (const float*)d_in[9];
    float* out = (float*)d_out;

    // 130 KB pack buffer (128 KB bf16 weights + 2 KB consts); fall back to the
    // (later overwritten) nfeat output region if the workspace is too small.
    u16* pack = (ws_size >= 133120) ? (u16*)d_ws : (u16*)(out + (size_t)EE * 128);

    hipFuncSetAttribute(reinterpret_cast<const void*>(edge_mlp_k),
                        hipFuncAttributeMaxDynamicSharedMemorySize, 133120);

    pack_weights_k<<<258, 256, 0, stream>>>(W1, W2, b1, b2, lng, lnb, pack);
    edge_mlp_k<<<256, 512, 133120, stream>>>(efeat, nfeat, srci, dsti, pack, out);
    copy_nfeat_k<<<2048, 256, 0, stream>>>((const float4*)nfeat,
                                           (float4*)(out + (size_t)EE * 128),
                                           (NN * 128) / 4);
}

// Round 7
// 1073.932 us; speedup vs baseline: 2.5891x; 2.1051x over previous
//
#include <hip/hip_runtime.h>
#include <cstdint>
#include <cstddef>

#define EE 1000000
#define NN 100000
#define NT 62500      // edge wave-tiles (16 edges each, exact)
#define NTN 6250      // node wave-tiles (16 nodes each, exact)

typedef unsigned short u16;
typedef __bf16 bf16x8 __attribute__((ext_vector_type(8)));
typedef float f32x4 __attribute__((ext_vector_type(4)));

__device__ __forceinline__ u16 f2bf(float f) {
    union { float f; uint32_t u; } v; v.f = f;
    uint32_t r = v.u + 0x7FFFu + ((v.u >> 16) & 1u);   // RNE
    return (u16)(r >> 16);
}
// RNE bf16 pair pack (compiler emits v_cvt_pk_bf16_f32): lo in bits[15:0]
__device__ __forceinline__ uint32_t cvt2(float lo, float hi) {
    u16 a = __builtin_bit_cast(u16, (__bf16)lo);
    u16 b = __builtin_bit_cast(u16, (__bf16)hi);
    return (uint32_t)a | ((uint32_t)b << 16);
}
__device__ __forceinline__ float bflo(uint32_t u) {
    union { uint32_t u; float f; } v; v.u = u << 16; return v.f;
}
__device__ __forceinline__ float bfhi(uint32_t u) {
    union { uint32_t u; float f; } v; v.u = u & 0xFFFF0000u; return v.f;
}

// ---------------- prep: pack weights into MFMA A-operand fragment streams.
// Frag formula (A-operand, 16x16x32): idx ((rt*4+kt)*64+lane)*8+j ->
//   W[koff + kt*32 + ((lane>>4)&3)*8 + j][rt*16 + (lane&15)]
// regions (u16 units): [0,16K) w1e (koff=0) | [16K,32K) w2 (K-perm, as R6)
//   | [32K,48K) w1s (koff=128) | [48K,64K) w1d (koff=256)
// consts at byte 131072 (f32): b1[128], b2[128], ln_g[128], ln_b[128]
__global__ void pack_weights_k(const float* __restrict__ W1, const float* __restrict__ W2,
                               const float* __restrict__ b1, const float* __restrict__ b2,
                               const float* __restrict__ lng, const float* __restrict__ lnb,
                               u16* __restrict__ pack) {
    int t = blockIdx.x * 256 + threadIdx.x;
    if (t >= 66048) return;
    if (t < 16384 || (t >= 32768 && t < 65536)) {
        int base = (t < 16384) ? 0 : (t < 49152) ? 32768 : 49152;
        int koff = (t < 16384) ? 0 : (t < 49152) ? 128 : 256;
        int u = t - base;
        int j = u & 7, lane = (u >> 3) & 63, kt = (u >> 9) & 3, rt = u >> 11;
        int k = koff + kt * 32 + ((lane >> 4) & 3) * 8 + j;
        pack[t] = f2bf(W1[k * 128 + rt * 16 + (lane & 15)]);
    } else if (t < 32768) {
        int u = t - 16384;
        int j = u & 7, lane = (u >> 3) & 63, kt2 = (u >> 9) & 3, ot = u >> 11;
        int hidden = 64 * (j >> 2) + 16 * kt2 + 4 * ((lane >> 4) & 3) + (j & 3);
        pack[t] = f2bf(W2[hidden * 128 + ot * 16 + (lane & 15)]);
    } else if (t < 66048) {
        int i = t - 65536;
        float v = (i < 128) ? b1[i] : (i < 256) ? b2[i - 128]
                : (i < 384) ? lng[i - 256] : lnb[i - 384];
        ((float*)(pack + 65536))[i] = v;
    }
}

// ---------------- node pass: uv[n] = [ u = W1s^T·nfeat[n] | v = W1d^T·nfeat[n] ]
// stored bf16 in MFMA-D distribution: uv[n*256 + hid] (u), uv[n*256+128+hid] (v)
__global__ void __launch_bounds__(256)
gen_uv_k(const float* __restrict__ nfeat, const u16* __restrict__ pack,
         u16* __restrict__ uv) {
    extern __shared__ char smem[];
    const u16* w1s = (const u16*)smem;            // 32 KB
    const u16* w1d = (const u16*)(smem + 32768);  // 32 KB
    const int tid = threadIdx.x;
    {
        const uint4* g = (const uint4*)(pack + 32768);  // bytes [65536,131072)
        uint4* l = (uint4*)smem;
#pragma unroll
        for (int i = 0; i < 16; i++) l[tid + i * 256] = g[tid + i * 256];
    }
    __syncthreads();
    const int lane = tid & 63, wid = tid >> 6;
    const int col = lane & 15, g4 = (lane >> 4) & 3;

    for (int nt = blockIdx.x * 4 + wid; nt < NTN; nt += (int)gridDim.x * 4) {
        const int n0 = nt * 16 + col;
        const float* rowN = nfeat + (size_t)n0 * 128;
        float4 nk[8];
#pragma unroll
        for (int q = 0; q < 4; q++) {
            const float4* p = (const float4*)(rowN + q * 32 + g4 * 8);
            nk[2 * q] = p[0]; nk[2 * q + 1] = p[1];
        }
        f32x4 au[8] = {}, av[8] = {};
#pragma unroll
        for (int kt = 0; kt < 4; kt++) {
            bf16x8 bf; uint32_t* bu = (uint32_t*)&bf;
            bu[0] = cvt2(nk[2 * kt].x, nk[2 * kt].y);
            bu[1] = cvt2(nk[2 * kt].z, nk[2 * kt].w);
            bu[2] = cvt2(nk[2 * kt + 1].x, nk[2 * kt + 1].y);
            bu[3] = cvt2(nk[2 * kt + 1].z, nk[2 * kt + 1].w);
#pragma unroll
            for (int rt = 0; rt < 8; rt++) {
                bf16x8 as = *(const bf16x8*)(w1s + ((rt * 4 + kt) * 64 + lane) * 8);
                bf16x8 ad = *(const bf16x8*)(w1d + ((rt * 4 + kt) * 64 + lane) * 8);
                au[rt] = __builtin_amdgcn_mfma_f32_16x16x32_bf16(as, bf, au[rt], 0, 0, 0);
                av[rt] = __builtin_amdgcn_mfma_f32_16x16x32_bf16(ad, bf, av[rt], 0, 0, 0);
            }
        }
        u16* urow = uv + (size_t)n0 * 256;
#pragma unroll
        for (int rt = 0; rt < 8; rt++) {
            uint2 pu, pv;
            pu.x = cvt2(au[rt][0], au[rt][1]); pu.y = cvt2(au[rt][2], au[rt][3]);
            pv.x = cvt2(av[rt][0], av[rt][1]); pv.y = cvt2(av[rt][2], av[rt][3]);
            *(uint2*)(urow + rt * 16 + g4 * 4) = pu;
            *(uint2*)(urow + 128 + rt * 16 + g4 * 4) = pv;
        }
    }
}

// ---------------- output[1] = nfeat passthrough
__global__ void copy_nfeat_k(const float4* __restrict__ s, float4* __restrict__ d, int n) {
    for (int i = blockIdx.x * blockDim.x + threadIdx.x; i < n; i += gridDim.x * blockDim.x)
        d[i] = s[i];
}

// ---------------- edge pass: h = silu(W1e·e + u[src] + v[dst] + b1);
// out = LN(h·W2 + b2) + e.  512 threads = 8 waves; 66.5 KB LDS -> 2 blocks/CU
// (16 waves). Barrier-free per-wave 16-edge tiles; all efeat reads index-free;
// node gather is 2 x 256 B bf16 per edge, issued a full GEMM1 before use.
__global__ void __launch_bounds__(512)
edge_mlp_k(const float* __restrict__ efeat, const int* __restrict__ srci,
           const int* __restrict__ dsti, const u16* __restrict__ uv,
           const u16* __restrict__ pack, float* __restrict__ out) {
    extern __shared__ char smem[];
    const u16* w1e = (const u16*)smem;               // 32 KB
    const u16* w2  = (const u16*)(smem + 32768);     // 32 KB
    const float* cst = (const float*)(smem + 65536); // 2 KB
    const int tid = threadIdx.x;
    {
        const uint4* g = (const uint4*)pack;   // 4096 uint4 = 64 KB
        uint4* l = (uint4*)smem;
#pragma unroll
        for (int i = 0; i < 8; i++) l[tid + i * 512] = g[tid + i * 512];
        ((float*)(smem + 65536))[tid] = ((const float*)(pack + 65536))[tid];
    }
    __syncthreads();

    const int lane = tid & 63, wid = tid >> 6;
    const int col = lane & 15, g4 = (lane >> 4) & 3;
    const float* cb1 = cst;
    const float* cb2 = cst + 128;
    const float* cg  = cst + 256;
    const float* cbb = cst + 384;

    int wt = blockIdx.x * 8 + wid;
    const int stride = (int)gridDim.x * 8;

    // prologue: current indices + full efeat row (q0..q3) in regs
    int e0 = wt * 16 + col;
    int sn = srci[e0], dn = dsti[e0];
    const float* rowE = efeat + (size_t)e0 * 128;
    float4 efk[8];
#pragma unroll
    for (int q = 0; q < 4; q++) {
        const float4* p = (const float4*)(rowE + q * 32 + g4 * 8);
        efk[2 * q] = p[0]; efk[2 * q + 1] = p[1];
    }

    for (; wt < NT; wt += stride) {
        // ---- u/v gathers for this tile (2 x 8 x 8B), land during GEMM1
        const u16* up = uv + (size_t)sn * 256;
        const u16* vp = uv + (size_t)dn * 256 + 128;
        uint2 ug[8], vg[8];
#pragma unroll
        for (int rt = 0; rt < 8; rt++) {
            ug[rt] = *(const uint2*)(up + rt * 16 + g4 * 4);
            vg[rt] = *(const uint2*)(vp + rt * 16 + g4 * 4);
        }

        // ---- GEMM1 (K=128, efeat only): 32 MFMAs, zero VMEM
        f32x4 acc1[8] = {};
#pragma unroll
        for (int kt = 0; kt < 4; kt++) {
            bf16x8 bf; uint32_t* bu = (uint32_t*)&bf;
            bu[0] = cvt2(efk[2 * kt].x, efk[2 * kt].y);
            bu[1] = cvt2(efk[2 * kt].z, efk[2 * kt].w);
            bu[2] = cvt2(efk[2 * kt + 1].x, efk[2 * kt + 1].y);
            bu[3] = cvt2(efk[2 * kt + 1].z, efk[2 * kt + 1].w);
#pragma unroll
            for (int rt = 0; rt < 8; rt++) {
                bf16x8 a = *(const bf16x8*)(w1e + ((rt * 4 + kt) * 64 + lane) * 8);
                acc1[rt] = __builtin_amdgcn_mfma_f32_16x16x32_bf16(a, bf, acc1[rt], 0, 0, 0);
            }
        }

        // ---- residual re-read (rowE just read -> L1/L2-hot) + next indices
        float4 ef4[8];
#pragma unroll
        for (int ot = 0; ot < 8; ot++)
            ef4[ot] = *(const float4*)(rowE + ot * 16 + g4 * 4);
        const int wtn = wt + stride;
        const int en = ((wtn < NT) ? wtn : wt) * 16 + col;
        const int sn1 = srci[en], dn1 = dsti[en];

        // ---- SiLU(acc1 + u + v + b1) -> packed bf16
        uint32_t hpk[8][2];
#pragma unroll
        for (int rt = 0; rt < 8; rt++) {
            float4 b1v = *(const float4*)(cb1 + rt * 16 + g4 * 4);
            float x0 = acc1[rt][0] + bflo(ug[rt].x) + bflo(vg[rt].x) + b1v.x;
            float x1 = acc1[rt][1] + bfhi(ug[rt].x) + bfhi(vg[rt].x) + b1v.y;
            float x2 = acc1[rt][2] + bflo(ug[rt].y) + bflo(vg[rt].y) + b1v.z;
            float x3 = acc1[rt][3] + bfhi(ug[rt].y) + bfhi(vg[rt].y) + b1v.w;
            float s0 = x0 / (1.f + __expf(-x0)), s1 = x1 / (1.f + __expf(-x1));
            float s2 = x2 / (1.f + __expf(-x2)), s3 = x3 / (1.f + __expf(-x3));
            hpk[rt][0] = cvt2(s0, s1);
            hpk[rt][1] = cvt2(s2, s3);
        }

        // ---- GEMM2 (+ prefetch next tile's efeat q0,q1 into freed efk slots)
        const float* rowEn = efeat + (size_t)en * 128;
        f32x4 acc2[8] = {};
#pragma unroll
        for (int kt2 = 0; kt2 < 4; kt2++) {
            bf16x8 bf; uint32_t* bu = (uint32_t*)&bf;
            bu[0] = hpk[kt2][0];     bu[1] = hpk[kt2][1];
            bu[2] = hpk[kt2 + 4][0]; bu[3] = hpk[kt2 + 4][1];
            if (kt2 < 2) {
                const float4* p = (const float4*)(rowEn + kt2 * 32 + g4 * 8);
                efk[2 * kt2] = p[0]; efk[2 * kt2 + 1] = p[1];
            }
#pragma unroll
            for (int ot = 0; ot < 8; ot++) {
                bf16x8 a = *(const bf16x8*)(w2 + ((ot * 4 + kt2) * 64 + lane) * 8);
                acc2[ot] = __builtin_amdgcn_mfma_f32_16x16x32_bf16(a, bf, acc2[ot], 0, 0, 0);
            }
        }

        // ---- + b2, LN stats
        float s = 0.f, q = 0.f;
#pragma unroll
        for (int ot = 0; ot < 8; ot++) {
            float4 b2v = *(const float4*)(cb2 + ot * 16 + g4 * 4);
#pragma unroll
            for (int r = 0; r < 4; r++) {
                float x = acc2[ot][r] + ((const float*)&b2v)[r];
                acc2[ot][r] = x;
                s += x; q += x * x;
            }
        }
        s += __shfl_xor(s, 16); q += __shfl_xor(q, 16);
        s += __shfl_xor(s, 32); q += __shfl_xor(q, 32);
        const float mean = s * (1.f / 128.f);
        const float rstd = rsqrtf(q * (1.f / 128.f) - mean * mean + 1e-5f);

        // ---- scale/shift + residual, store
        float* op = out + (size_t)(wt * 16 + col) * 128;
#pragma unroll
        for (int ot = 0; ot < 8; ot++) {
            float4 gv = *(const float4*)(cg + ot * 16 + g4 * 4);
            float4 bv = *(const float4*)(cbb + ot * 16 + g4 * 4);
            float4 o;
            o.x = (acc2[ot][0] - mean) * rstd * gv.x + bv.x + ef4[ot].x;
            o.y = (acc2[ot][1] - mean) * rstd * gv.y + bv.y + ef4[ot].y;
            o.z = (acc2[ot][2] - mean) * rstd * gv.z + bv.z + ef4[ot].z;
            o.w = (acc2[ot][3] - mean) * rstd * gv.w + bv.w + ef4[ot].w;
            *(float4*)(op + ot * 16 + g4 * 4) = o;
        }

        // ---- prefetch next tile's efeat q2,q3; roll state
#pragma unroll
        for (int q2 = 2; q2 < 4; q2++) {
            const float4* p = (const float4*)(rowEn + q2 * 32 + g4 * 8);
            efk[2 * q2] = p[0]; efk[2 * q2 + 1] = p[1];
        }
        rowE = rowEn; sn = sn1; dn = dn1;
    }
}

extern "C" void kernel_launch(void* const* d_in, const int* in_sizes, int n_in,
                              void* d_out, int out_size, void* d_ws, size_t ws_size,
                              hipStream_t stream) {
    const float* efeat = (const float*)d_in[0];
    const float* nfeat = (const float*)d_in[1];
    const int* srci = (const int*)d_in[2];
    const int* dsti = (const int*)d_in[3];
    const float* W1 = (const float*)d_in[4];
    const float* b1 = (const float*)d_in[5];
    const float* W2 = (const float*)d_in[6];
    const float* b2 = (const float*)d_in[7];
    const float* lng = (const float*)d_in[8];
    const float* lnb = (const float*)d_in[9];
    float* out = (float*)d_out;

    const size_t pack_bytes = 133120;                 // 128 KB frags + 2 KB consts
    const size_t uv_bytes = (size_t)NN * 256 * 2;     // 51.2 MB bf16 uv
    u16 *pack, *uvb;
    if (ws_size >= pack_bytes + uv_bytes) {
        pack = (u16*)d_ws;
        uvb = (u16*)((char*)d_ws + pack_bytes);
    } else if (ws_size >= uv_bytes) {
        uvb = (u16*)d_ws;
        pack = (u16*)(out + (size_t)EE * 128);        // nfeat region; copy runs last
    } else {
        uvb = (u16*)(out + (size_t)EE * 128);         // exact fit; copy runs last
        pack = (ws_size >= pack_bytes) ? (u16*)d_ws
             : (u16*)(out + (size_t)EE * 128 - 33280); // edge-out tail (written last)
    }

    hipFuncSetAttribute(reinterpret_cast<const void*>(gen_uv_k),
                        hipFuncAttributeMaxDynamicSharedMemorySize, 65536);
    hipFuncSetAttribute(reinterpret_cast<const void*>(edge_mlp_k),
                        hipFuncAttributeMaxDynamicSharedMemorySize, 67584);

    pack_weights_k<<<258, 256, 0, stream>>>(W1, W2, b1, b2, lng, lnb, pack);
    gen_uv_k<<<512, 256, 65536, stream>>>(nfeat, pack, uvb);
    edge_mlp_k<<<512, 512, 67584, stream>>>(efeat, srci, dsti, uvb, pack, out);
    copy_nfeat_k<<<2048, 256, 0, stream>>>((const float4*)nfeat,
                                           (float4*)(out + (size_t)EE * 128),
                                           (NN * 128) / 4);
}